// Round 1
// baseline (1777.815 us; speedup 1.0000x reference)
//
#include <hip/hip_runtime.h>
#include <math.h>

#define BATCH 4
#define NQ 2048
#define NKEY 2048
#define DMODEL 512
#define NH 8
#define DHEAD 64
#define BH (BATCH * NH)

// ---------------------------------------------------------------------------
// Generic tiled f32 GEMM: C = A[M,K] @ W[K,N], 64x64 tile, BK=16, 256 thr, 4x4/thr
// MODE 0: C row-major [M,N]
// MODE 1: head-split epilogue: C[((b*NH+h)*2048 + s)*64 + d], m=b*2048+s, n=h*64+d
// MODE 2: C = resid - (acc + bias[n])
// MODE 3: C = acc + bias[n]
// ---------------------------------------------------------------------------
template <int MODE>
__launch_bounds__(256) __global__
void gemm_f32(const float* __restrict__ A, const float* __restrict__ W,
              float* __restrict__ C, const float* __restrict__ bias,
              const float* __restrict__ resid, int M, int N, int K) {
    __shared__ float As[16][68];  // transposed: As[k][m], stride 68 floats = 16B-aligned rows
    __shared__ float Ws[16][64];  // Ws[k][n]
    const int tid = threadIdx.x;
    const int m0 = blockIdx.x * 64;
    const int n0 = blockIdx.y * 64;
    const int tx = tid & 15, ty = tid >> 4;
    float acc[4][4] = {};
    for (int k0 = 0; k0 < K; k0 += 16) {
        // A tile: 64 rows x 16 k  (store transposed into As[k][m])
        #pragma unroll
        for (int p = 0; p < 4; ++p) {
            int r = (tid >> 4) + p * 16;
            int c = tid & 15;
            As[c][r] = A[(size_t)(m0 + r) * K + k0 + c];
        }
        // W tile: 16 k x 64 n
        #pragma unroll
        for (int p = 0; p < 4; ++p) {
            int r = (tid >> 6) + p * 4;
            int c = tid & 63;
            Ws[r][c] = W[(size_t)(k0 + r) * N + n0 + c];
        }
        __syncthreads();
        #pragma unroll
        for (int kk = 0; kk < 16; ++kk) {
            float4 a = *(const float4*)&As[kk][ty * 4];
            float4 w = *(const float4*)&Ws[kk][tx * 4];
            float av[4] = {a.x, a.y, a.z, a.w};
            float wv[4] = {w.x, w.y, w.z, w.w};
            #pragma unroll
            for (int i = 0; i < 4; ++i)
                #pragma unroll
                for (int j = 0; j < 4; ++j)
                    acc[i][j] += av[i] * wv[j];
        }
        __syncthreads();
    }
    #pragma unroll
    for (int i = 0; i < 4; ++i) {
        int m = m0 + ty * 4 + i;
        #pragma unroll
        for (int j = 0; j < 4; ++j) {
            int n = n0 + tx * 4 + j;
            float v = acc[i][j];
            if (MODE == 0) {
                C[(size_t)m * N + n] = v;
            } else if (MODE == 1) {
                int b = m >> 11, s = m & 2047;
                int h = n >> 6, d = n & 63;
                C[(((size_t)(b * NH + h) * 2048) + s) * 64 + d] = v;
            } else if (MODE == 2) {
                C[(size_t)m * N + n] = resid[(size_t)m * N + n] - (v + bias[n]);
            } else {
                C[(size_t)m * N + n] = v + bias[n];
            }
        }
    }
}

// ---------------------------------------------------------------------------
// Pass 1: per-head column stats over the query axis.
// For each (bh, k): m_k = max_q S[q,k], s_k = sum_q exp(S[q,k]-m_k)
// Block handles 64 k-columns, iterates all 2048 q in 32-row tiles (online merge).
// ---------------------------------------------------------------------------
__launch_bounds__(256) __global__
void attn_pass1(const float* __restrict__ Qh, const float* __restrict__ Kh,
                float* __restrict__ colM, float* __restrict__ colS) {
    __shared__ float Kt[64][68];
    __shared__ float Qs[32][68];
    __shared__ float Ss[32][65];
    __shared__ float runM[64], runS[64];
    __shared__ float pM[4][64], pS[4][64];
    const int tid = threadIdx.x;
    const int k0 = blockIdx.x * 64;
    const int bh = blockIdx.y;
    const float* Kbase = Kh + (size_t)bh * NKEY * DHEAD;
    const float* Qbase = Qh + (size_t)bh * NQ * DHEAD;
    #pragma unroll
    for (int p = 0; p < 16; ++p) {
        int idx = tid + p * 256;
        Kt[idx >> 6][idx & 63] = Kbase[(size_t)(k0 + (idx >> 6)) * DHEAD + (idx & 63)];
    }
    if (tid < 64) { runM[tid] = -INFINITY; runS[tid] = 0.f; }
    __syncthreads();
    const int tq = (tid >> 4) * 2;  // 0..30
    const int tk = (tid & 15) * 4;  // 0..60
    for (int q0 = 0; q0 < NQ; q0 += 32) {
        #pragma unroll
        for (int p = 0; p < 8; ++p) {
            int idx = tid + p * 256;
            Qs[idx >> 6][idx & 63] = Qbase[(size_t)(q0 + (idx >> 6)) * DHEAD + (idx & 63)];
        }
        __syncthreads();
        float s[2][4] = {};
        #pragma unroll
        for (int d = 0; d < 64; d += 4) {
            float4 a0 = *(const float4*)&Qs[tq][d];
            float4 a1 = *(const float4*)&Qs[tq + 1][d];
            #pragma unroll
            for (int j = 0; j < 4; ++j) {
                float4 kv = *(const float4*)&Kt[tk + j][d];
                s[0][j] += a0.x * kv.x + a0.y * kv.y + a0.z * kv.z + a0.w * kv.w;
                s[1][j] += a1.x * kv.x + a1.y * kv.y + a1.z * kv.z + a1.w * kv.w;
            }
        }
        #pragma unroll
        for (int i = 0; i < 2; ++i)
            #pragma unroll
            for (int j = 0; j < 4; ++j)
                Ss[tq + i][tk + j] = s[i][j];
        __syncthreads();
        {   // partial stats: 4 partitions of 8 q-rows each, all 256 threads busy
            int col = tid & 63, part = tid >> 6;
            float m = -INFINITY;
            #pragma unroll
            for (int q = 0; q < 8; ++q) m = fmaxf(m, Ss[part * 8 + q][col]);
            float sum = 0.f;
            #pragma unroll
            for (int q = 0; q < 8; ++q) sum += __expf(Ss[part * 8 + q][col] - m);
            pM[part][col] = m; pS[part][col] = sum;
        }
        __syncthreads();
        if (tid < 64) {
            float M0 = runM[tid], S0 = runS[tid];
            float m = M0;
            #pragma unroll
            for (int p = 0; p < 4; ++p) m = fmaxf(m, pM[p][tid]);
            float snew = S0 * __expf(M0 - m);  // first iter: 0 * 0 = 0
            #pragma unroll
            for (int p = 0; p < 4; ++p) snew += pS[p][tid] * __expf(pM[p][tid] - m);
            runM[tid] = m; runS[tid] = snew;
        }
        __syncthreads();
    }
    if (tid < 64) {
        colM[(size_t)bh * NKEY + k0 + tid] = runM[tid];
        colS[(size_t)bh * NKEY + k0 + tid] = runS[tid];
    }
}

// ---------------------------------------------------------------------------
// Pass 2: recompute S tiles, E = exp(S - m_k)/s_k, r_q = sum_k E, O = E @ V,
// write attn[(b*NQ + q)*512 + h*64 + d] = O / (1e-12 + r_q).
// Block: 32 q-rows of one head, loops over all k in 32-tiles.
// ---------------------------------------------------------------------------
__launch_bounds__(256) __global__
void attn_pass2(const float* __restrict__ Qh, const float* __restrict__ Kh,
                const float* __restrict__ Vh, const float* __restrict__ colM,
                const float* __restrict__ colS, float* __restrict__ attn) {
    __shared__ float Qs[32][68];
    __shared__ float Kt[32][68];
    __shared__ float Vs[32][68];
    __shared__ float Es[32][33];
    __shared__ float cmS[32], rcsS[32];
    const int tid = threadIdx.x;
    const int q0 = blockIdx.x * 32;
    const int bh = blockIdx.y;
    const int b = bh >> 3, h = bh & 7;
    const float* Qbase = Qh + (size_t)bh * NQ * DHEAD;
    const float* Kbase = Kh + (size_t)bh * NKEY * DHEAD;
    const float* Vbase = Vh + (size_t)bh * NKEY * DHEAD;
    #pragma unroll
    for (int p = 0; p < 8; ++p) {
        int idx = tid + p * 256;
        Qs[idx >> 6][idx & 63] = Qbase[(size_t)(q0 + (idx >> 6)) * DHEAD + (idx & 63)];
    }
    float O[8] = {};
    float r = 0.f;
    const int tq2 = (tid >> 4) * 2;
    const int tk2 = (tid & 15) * 2;
    const int q_l = tid >> 3;
    const int d_b = (tid & 7) * 8;
    for (int kt0 = 0; kt0 < NKEY; kt0 += 32) {
        __syncthreads();  // protects Kt/Vs/Es from previous iter; covers Qs on iter 0
        #pragma unroll
        for (int p = 0; p < 8; ++p) {
            int idx = tid + p * 256;
            Kt[idx >> 6][idx & 63] = Kbase[(size_t)(kt0 + (idx >> 6)) * DHEAD + (idx & 63)];
        }
        #pragma unroll
        for (int p = 0; p < 8; ++p) {
            int idx = tid + p * 256;
            Vs[idx >> 6][idx & 63] = Vbase[(size_t)(kt0 + (idx >> 6)) * DHEAD + (idx & 63)];
        }
        if (tid < 32) {
            cmS[tid] = colM[(size_t)bh * NKEY + kt0 + tid];
            rcsS[tid] = 1.0f / colS[(size_t)bh * NKEY + kt0 + tid];  // colS >= 1 always
        }
        __syncthreads();
        float s2[2][2] = {};
        #pragma unroll
        for (int d = 0; d < 64; d += 4) {
            float4 a0 = *(const float4*)&Qs[tq2][d];
            float4 a1 = *(const float4*)&Qs[tq2 + 1][d];
            float4 k0v = *(const float4*)&Kt[tk2][d];
            float4 k1v = *(const float4*)&Kt[tk2 + 1][d];
            s2[0][0] += a0.x * k0v.x + a0.y * k0v.y + a0.z * k0v.z + a0.w * k0v.w;
            s2[0][1] += a0.x * k1v.x + a0.y * k1v.y + a0.z * k1v.z + a0.w * k1v.w;
            s2[1][0] += a1.x * k0v.x + a1.y * k0v.y + a1.z * k0v.z + a1.w * k0v.w;
            s2[1][1] += a1.x * k1v.x + a1.y * k1v.y + a1.z * k1v.z + a1.w * k1v.w;
        }
        #pragma unroll
        for (int i = 0; i < 2; ++i)
            #pragma unroll
            for (int j = 0; j < 2; ++j)
                Es[tq2 + i][tk2 + j] = __expf(s2[i][j] - cmS[tk2 + j]) * rcsS[tk2 + j];
        __syncthreads();
        #pragma unroll 8
        for (int kk = 0; kk < 32; ++kk) {
            float e = Es[q_l][kk];
            r += e;
            float4 v0 = *(const float4*)&Vs[kk][d_b];
            float4 v1 = *(const float4*)&Vs[kk][d_b + 4];
            O[0] += e * v0.x; O[1] += e * v0.y; O[2] += e * v0.z; O[3] += e * v0.w;
            O[4] += e * v1.x; O[5] += e * v1.y; O[6] += e * v1.z; O[7] += e * v1.w;
        }
    }
    float scale = 1.0f / (1e-12f + r);
    size_t base = ((size_t)b * NQ + q0 + q_l) * DMODEL + h * 64 + d_b;
    #pragma unroll
    for (int j = 0; j < 8; ++j) attn[base + j] = O[j] * scale;
}

// ---------------------------------------------------------------------------
extern "C" void kernel_launch(void* const* d_in, const int* in_sizes, int n_in,
                              void* d_out, int out_size, void* d_ws, size_t ws_size,
                              hipStream_t stream) {
    const float* init_query = (const float*)d_in[0];
    const float* embedding  = (const float*)d_in[1];
    const float* Wq = (const float*)d_in[2];
    const float* Wk = (const float*)d_in[3];
    const float* Wv = (const float*)d_in[4];
    const float* W0 = (const float*)d_in[5];
    const float* b0 = (const float*)d_in[6];
    const float* W1 = (const float*)d_in[7];
    const float* b1 = (const float*)d_in[8];
    float* out = (float*)d_out;

    // workspace layout (floats): Q | K | V | colM | colS | attn ; y aliases Q
    float* Qh   = (float*)d_ws;
    float* Kh   = Qh + (size_t)BH * NKEY * DHEAD;
    float* Vh   = Kh + (size_t)BH * NKEY * DHEAD;
    float* cM   = Vh + (size_t)BH * NKEY * DHEAD;
    float* cS   = cM + (size_t)BH * NKEY;
    float* attn = cS + (size_t)BH * NKEY;
    float* ybuf = Qh;  // Q dead after pass2; W0-gemm runs strictly after on stream

    const int M = BATCH * NQ;  // 8192
    dim3 gg(M / 64, DMODEL / 64), blk(256);

    gemm_f32<1><<<gg, blk, 0, stream>>>(init_query, Wq, Qh, nullptr, nullptr, M, DMODEL, DMODEL);
    gemm_f32<1><<<gg, blk, 0, stream>>>(embedding,  Wk, Kh, nullptr, nullptr, M, DMODEL, DMODEL);
    gemm_f32<1><<<gg, blk, 0, stream>>>(embedding,  Wv, Vh, nullptr, nullptr, M, DMODEL, DMODEL);

    attn_pass1<<<dim3(NKEY / 64, BH), blk, 0, stream>>>(Qh, Kh, cM, cS);
    attn_pass2<<<dim3(NQ / 32, BH),  blk, 0, stream>>>(Qh, Kh, Vh, cM, cS, attn);

    gemm_f32<2><<<gg, blk, 0, stream>>>(attn, W0, ybuf, b0, init_query, M, DMODEL, DMODEL);
    gemm_f32<3><<<gg, blk, 0, stream>>>(ybuf, W1, out, b1, nullptr, M, DMODEL, DMODEL);
}

// Round 2
// 566.382 us; speedup vs baseline: 3.1389x; 3.1389x over previous
//
#include <hip/hip_runtime.h>
#include <math.h>

#define BATCH 4
#define NQ 2048
#define NKEY 2048
#define DMODEL 512
#define NH 8
#define DHEAD 64
#define BH (BATCH * NH)

typedef __attribute__((ext_vector_type(8))) short short8;
typedef __attribute__((ext_vector_type(4))) float f32x4;

#define MFMA16(a, b, c) __builtin_amdgcn_mfma_f32_16x16x32_bf16((a), (b), (c), 0, 0, 0)

// f32 -> bf16 bits, round-to-nearest-even
static __device__ __forceinline__ unsigned short f2b(float f) {
    union { float f; unsigned u; } v; v.f = f;
    unsigned r = (v.u + 0x7fffu + ((v.u >> 16) & 1u)) >> 16;
    return (unsigned short)r;
}

// ---------------------------------------------------------------------------
// Cast both activations f32 -> bf16 (row-major [8192,512])
// ---------------------------------------------------------------------------
__launch_bounds__(256) __global__
void cast_x(const float* __restrict__ a, const float* __restrict__ b,
            unsigned short* __restrict__ da, unsigned short* __restrict__ db) {
    const float* s = blockIdx.y ? b : a;
    unsigned short* d = blockIdx.y ? db : da;
    size_t i = ((size_t)blockIdx.x * 256 + threadIdx.x) * 4;
    float4 v = *(const float4*)(s + i);
    ushort4 o;
    o.x = f2b(v.x); o.y = f2b(v.y); o.z = f2b(v.z); o.w = f2b(v.w);
    *(ushort4*)(d + i) = o;
}

// ---------------------------------------------------------------------------
// Transpose+cast the five 512x512 weights: Wt[n][k] = bf16(W[k][n])
// ---------------------------------------------------------------------------
__launch_bounds__(256) __global__
void trans_w(const float* __restrict__ w0, const float* __restrict__ w1,
             const float* __restrict__ w2, const float* __restrict__ w3,
             const float* __restrict__ w4, unsigned short* __restrict__ dst) {
    const float* src = (blockIdx.z == 0) ? w0 : (blockIdx.z == 1) ? w1 :
                       (blockIdx.z == 2) ? w2 : (blockIdx.z == 3) ? w3 : w4;
    unsigned short* out = dst + (size_t)blockIdx.z * DMODEL * DMODEL;
    __shared__ float t[32][33];
    const int tx = threadIdx.x & 31, ty = threadIdx.x >> 5;  // 32 x 8
    const int k0 = blockIdx.x * 32, n0 = blockIdx.y * 32;
    #pragma unroll
    for (int j = 0; j < 4; ++j)
        t[ty + j * 8][tx] = src[(size_t)(k0 + ty + j * 8) * DMODEL + n0 + tx];
    __syncthreads();
    #pragma unroll
    for (int j = 0; j < 4; ++j)
        out[(size_t)(n0 + ty + j * 8) * DMODEL + k0 + tx] = f2b(t[tx][ty + j * 8]);
}

// ---------------------------------------------------------------------------
// bf16 MFMA GEMM, direct-global fragments (no LDS).
// A [M,K] bf16 row-major; Bt [N,K] bf16 (transposed weights). Block 256 = 4
// waves; wave covers 32 m-rows x 64 n-cols; block tile 128x64. BK=32.
// MODE 0: head-split bf16 store  C[((b*8+h)*2048+s)*64+d]
// MODE 1: V-transposed bf16 store Vt[((b*8+h)*64+d)*2048+s]
// MODE 2: bf16 store  C[m*N+n] = bf16(resid - (acc + bias[n]))
// MODE 3: f32 store   C[m*N+n] = acc + bias[n]
// ---------------------------------------------------------------------------
template <int MODE>
__launch_bounds__(256) __global__
void gemm_bf16(const unsigned short* __restrict__ A,
               const unsigned short* __restrict__ Bt,
               void* __restrict__ Cout, const float* __restrict__ bias,
               const float* __restrict__ resid, int M, int N, int K) {
    const int tid = threadIdx.x;
    const int w = tid >> 6, lane = tid & 63;
    const int l16 = lane & 15, q4 = lane >> 4;
    const int mBase = blockIdx.x * 128 + w * 32;
    const int n0 = blockIdx.y * 64;

    const unsigned short* Arow0 = A + (size_t)(mBase + l16) * K;
    const unsigned short* Arow1 = Arow0 + (size_t)16 * K;
    const unsigned short* Brow0 = Bt + (size_t)(n0 + l16) * K;

    f32x4 z = {0.f, 0.f, 0.f, 0.f};
    f32x4 acc[2][4];
    #pragma unroll
    for (int i = 0; i < 2; ++i)
        #pragma unroll
        for (int t = 0; t < 4; ++t) acc[i][t] = z;

    #pragma unroll 2
    for (int k0 = 0; k0 < K; k0 += 32) {
        const int ko = k0 + q4 * 8;
        short8 a0 = *(const short8*)(Arow0 + ko);
        short8 a1 = *(const short8*)(Arow1 + ko);
        #pragma unroll
        for (int t = 0; t < 4; ++t) {
            short8 b = *(const short8*)(Brow0 + (size_t)t * 16 * K + ko);
            acc[0][t] = MFMA16(a0, b, acc[0][t]);
            acc[1][t] = MFMA16(a1, b, acc[1][t]);
        }
    }

    #pragma unroll
    for (int i = 0; i < 2; ++i) {
        #pragma unroll
        for (int t = 0; t < 4; ++t) {
            #pragma unroll
            for (int r = 0; r < 4; ++r) {
                const int m = mBase + i * 16 + q4 * 4 + r;
                const int n = n0 + t * 16 + l16;
                float v = acc[i][t][r];
                if (MODE == 0) {
                    ((unsigned short*)Cout)[(((size_t)(m >> 11) * NH + (n >> 6)) * NQ + (m & 2047)) * DHEAD + (n & 63)] = f2b(v);
                } else if (MODE == 1) {
                    ((unsigned short*)Cout)[(((size_t)(m >> 11) * NH + (n >> 6)) * DHEAD + (n & 63)) * NKEY + (m & 2047)] = f2b(v);
                } else if (MODE == 2) {
                    ((unsigned short*)Cout)[(size_t)m * N + n] = f2b(resid[(size_t)m * N + n] - (v + bias[n]));
                } else {
                    ((float*)Cout)[(size_t)m * N + n] = v + bias[n];
                }
            }
        }
    }
}

// ---------------------------------------------------------------------------
// Pass 1: colSrcp[bh][k] = 1 / sum_q exp(S[q,k])  (no max subtraction; |S|<~10)
// Block = 4 waves x 16 k-cols = 64 k per block. Wave loops q in steps of 16.
// ---------------------------------------------------------------------------
__launch_bounds__(256) __global__
void attn_pass1(const unsigned short* __restrict__ Qh,
                const unsigned short* __restrict__ Kh,
                float* __restrict__ colSrcp) {
    const int tid = threadIdx.x;
    const int w = tid >> 6, lane = tid & 63;
    const int l16 = lane & 15, q4 = lane >> 4;
    const int bh = blockIdx.y;
    const int kcol0 = blockIdx.x * 64 + w * 16;

    const unsigned short* Krow = Kh + ((size_t)bh * NKEY + kcol0 + l16) * DHEAD;
    short8 bk0 = *(const short8*)(Krow + q4 * 8);
    short8 bk1 = *(const short8*)(Krow + 32 + q4 * 8);
    const unsigned short* Qb = Qh + (size_t)bh * NQ * DHEAD;

    float csum = 0.f;
    for (int q0 = 0; q0 < NQ; q0 += 16) {
        const unsigned short* Arow = Qb + (size_t)(q0 + l16) * DHEAD;
        short8 a0 = *(const short8*)(Arow + q4 * 8);
        short8 a1 = *(const short8*)(Arow + 32 + q4 * 8);
        f32x4 s = {0.f, 0.f, 0.f, 0.f};
        s = MFMA16(a0, bk0, s);
        s = MFMA16(a1, bk1, s);
        csum += __expf(s[0]) + __expf(s[1]) + __expf(s[2]) + __expf(s[3]);
    }
    csum += __shfl_xor(csum, 16, 64);
    csum += __shfl_xor(csum, 32, 64);
    if (q4 == 0)
        colSrcp[(size_t)bh * NKEY + kcol0 + l16] = 1.0f / csum;
}

// ---------------------------------------------------------------------------
// Pass 2: E = exp(S)*colSrcp; r_q = sum_k E; O = E @ V; attnb = bf16(O / (1e-12+r_q))
// Block = 4 waves x 16 q-rows = 64 q per block. Wave loops k in steps of 32.
// E goes C-layout -> LDS (wave-private, stride 40 bf16) -> A-fragment.
// No __syncthreads: each wave uses its own LDS region; same-wave DS ops are ordered.
// ---------------------------------------------------------------------------
__launch_bounds__(256) __global__
void attn_pass2(const unsigned short* __restrict__ Qh,
                const unsigned short* __restrict__ Kh,
                const unsigned short* __restrict__ Vt,
                const float* __restrict__ colSrcp,
                unsigned short* __restrict__ attnb) {
    __shared__ unsigned short Elds[4][16][40];
    const int tid = threadIdx.x;
    const int w = tid >> 6, lane = tid & 63;
    const int l16 = lane & 15, q4 = lane >> 4;
    const int bh = blockIdx.y;
    const int b = bh >> 3, h = bh & 7;
    const int q0 = blockIdx.x * 64 + w * 16;

    const unsigned short* Qrow = Qh + ((size_t)bh * NQ + q0 + l16) * DHEAD;
    short8 aq0 = *(const short8*)(Qrow + q4 * 8);
    short8 aq1 = *(const short8*)(Qrow + 32 + q4 * 8);
    const unsigned short* Kb = Kh + (size_t)bh * NKEY * DHEAD;
    const unsigned short* Vb = Vt + (size_t)bh * DHEAD * NKEY;
    const float* cs = colSrcp + (size_t)bh * NKEY;
    unsigned short* Ew = &Elds[w][0][0];

    f32x4 z = {0.f, 0.f, 0.f, 0.f};
    f32x4 o[4];
    #pragma unroll
    for (int t = 0; t < 4; ++t) o[t] = z;
    float rq[4] = {0.f, 0.f, 0.f, 0.f};

    for (int k0 = 0; k0 < NKEY; k0 += 32) {
        #pragma unroll
        for (int t = 0; t < 2; ++t) {
            const unsigned short* Krow = Kb + (size_t)(k0 + t * 16 + l16) * DHEAD;
            short8 b0 = *(const short8*)(Krow + q4 * 8);
            short8 b1 = *(const short8*)(Krow + 32 + q4 * 8);
            f32x4 s = z;
            s = MFMA16(aq0, b0, s);
            s = MFMA16(aq1, b1, s);
            float rcp = cs[k0 + t * 16 + l16];
            #pragma unroll
            for (int r = 0; r < 4; ++r) {
                float e = __expf(s[r]) * rcp;
                rq[r] += e;
                Ew[(q4 * 4 + r) * 40 + t * 16 + l16] = f2b(e);
            }
        }
        short8 ea = *(const short8*)(Ew + l16 * 40 + q4 * 8);
        #pragma unroll
        for (int t = 0; t < 4; ++t) {
            short8 bv = *(const short8*)(Vb + (size_t)(t * 16 + l16) * NKEY + k0 + q4 * 8);
            o[t] = MFMA16(ea, bv, o[t]);
        }
    }

    #pragma unroll
    for (int r = 0; r < 4; ++r) {
        float v = rq[r];
        v += __shfl_xor(v, 1, 64);
        v += __shfl_xor(v, 2, 64);
        v += __shfl_xor(v, 4, 64);
        v += __shfl_xor(v, 8, 64);
        rq[r] = 1.0f / (1e-12f + v);
    }
    #pragma unroll
    for (int t = 0; t < 4; ++t) {
        #pragma unroll
        for (int r = 0; r < 4; ++r) {
            const int q = q0 + q4 * 4 + r;
            attnb[((size_t)b * NQ + q) * DMODEL + h * DHEAD + t * 16 + l16] = f2b(o[t][r] * rq[r]);
        }
    }
}

// ---------------------------------------------------------------------------
extern "C" void kernel_launch(void* const* d_in, const int* in_sizes, int n_in,
                              void* d_out, int out_size, void* d_ws, size_t ws_size,
                              hipStream_t stream) {
    const float* init_query = (const float*)d_in[0];
    const float* embedding  = (const float*)d_in[1];
    const float* Wq = (const float*)d_in[2];
    const float* Wk = (const float*)d_in[3];
    const float* Wv = (const float*)d_in[4];
    const float* W0 = (const float*)d_in[5];
    const float* b0 = (const float*)d_in[6];
    const float* W1 = (const float*)d_in[7];
    const float* b1 = (const float*)d_in[8];
    float* out = (float*)d_out;

    const size_t ACT = (size_t)BATCH * NQ * DMODEL;   // 4M elements
    const size_t WEL = (size_t)DMODEL * DMODEL;       // 256K elements

    unsigned short* Xq   = (unsigned short*)d_ws;          // bf16 init_query
    unsigned short* Xe   = Xq + ACT;                       // bf16 embedding
    unsigned short* Wt   = Xe + ACT;                       // 5 transposed weights
    unsigned short* Qh   = Wt + 5 * WEL;                   // [bh][q][d]
    unsigned short* Kh   = Qh + ACT;                       // [bh][k][d]
    unsigned short* Vtb  = Kh + ACT;                       // [bh][d][k]
    unsigned short* attnb= Vtb + ACT;                      // [8192][512]
    unsigned short* ybuf = attnb + ACT;                    // [8192][512]
    float* colSrcp = (float*)(ybuf + ACT);                 // [bh][k]

    unsigned short* Wqt = Wt + 0 * WEL;
    unsigned short* Wkt = Wt + 1 * WEL;
    unsigned short* Wvt = Wt + 2 * WEL;
    unsigned short* W0t = Wt + 3 * WEL;
    unsigned short* W1t = Wt + 4 * WEL;

    const int M = BATCH * NQ;  // 8192
    dim3 blk(256);
    dim3 gGemm(M / 128, DMODEL / 64);  // 64 x 8

    cast_x<<<dim3(ACT / 1024, 2), blk, 0, stream>>>(init_query, embedding, Xq, Xe);
    trans_w<<<dim3(16, 16, 5), blk, 0, stream>>>(Wq, Wk, Wv, W0, W1, Wt);

    gemm_bf16<0><<<gGemm, blk, 0, stream>>>(Xq, Wqt, Qh, nullptr, nullptr, M, DMODEL, DMODEL);
    gemm_bf16<0><<<gGemm, blk, 0, stream>>>(Xe, Wkt, Kh, nullptr, nullptr, M, DMODEL, DMODEL);
    gemm_bf16<1><<<gGemm, blk, 0, stream>>>(Xe, Wvt, Vtb, nullptr, nullptr, M, DMODEL, DMODEL);

    attn_pass1<<<dim3(NKEY / 64, BH), blk, 0, stream>>>(Qh, Kh, colSrcp);
    attn_pass2<<<dim3(NQ / 64, BH), blk, 0, stream>>>(Qh, Kh, Vtb, colSrcp, attnb);

    gemm_bf16<2><<<gGemm, blk, 0, stream>>>(attnb, W0t, ybuf, b0, init_query, M, DMODEL, DMODEL);
    gemm_bf16<3><<<gGemm, blk, 0, stream>>>(ybuf, W1t, out, b1, nullptr, M, DMODEL, DMODEL);
}

// Round 3
// 400.390 us; speedup vs baseline: 4.4402x; 1.4146x over previous
//
#include <hip/hip_runtime.h>
#include <math.h>

#define BATCH 4
#define NQ 2048
#define NKEY 2048
#define DMODEL 512
#define NH 8
#define DHEAD 64
#define BH (BATCH * NH)

typedef __attribute__((ext_vector_type(8))) short short8;
typedef __attribute__((ext_vector_type(4))) float f32x4;

#define MFMA16(a, b, c) __builtin_amdgcn_mfma_f32_16x16x32_bf16((a), (b), (c), 0, 0, 0)

// f32 -> bf16 bits, round-to-nearest-even
static __device__ __forceinline__ unsigned short f2b(float f) {
    union { float f; unsigned u; } v; v.f = f;
    unsigned r = (v.u + 0x7fffu + ((v.u >> 16) & 1u)) >> 16;
    return (unsigned short)r;
}

// ---------------------------------------------------------------------------
// Cast both activations f32 -> bf16 (row-major [8192,512])
// ---------------------------------------------------------------------------
__launch_bounds__(256) __global__
void cast_x(const float* __restrict__ a, const float* __restrict__ b,
            unsigned short* __restrict__ da, unsigned short* __restrict__ db) {
    const float* s = blockIdx.y ? b : a;
    unsigned short* d = blockIdx.y ? db : da;
    size_t i = ((size_t)blockIdx.x * 256 + threadIdx.x) * 4;
    float4 v = *(const float4*)(s + i);
    ushort4 o;
    o.x = f2b(v.x); o.y = f2b(v.y); o.z = f2b(v.z); o.w = f2b(v.w);
    *(ushort4*)(d + i) = o;
}

// ---------------------------------------------------------------------------
// Transpose+cast the five 512x512 weights: Wt[n][k] = bf16(W[k][n])
// ---------------------------------------------------------------------------
__launch_bounds__(256) __global__
void trans_w(const float* __restrict__ w0, const float* __restrict__ w1,
             const float* __restrict__ w2, const float* __restrict__ w3,
             const float* __restrict__ w4, unsigned short* __restrict__ dst) {
    const float* src = (blockIdx.z == 0) ? w0 : (blockIdx.z == 1) ? w1 :
                       (blockIdx.z == 2) ? w2 : (blockIdx.z == 3) ? w3 : w4;
    unsigned short* out = dst + (size_t)blockIdx.z * DMODEL * DMODEL;
    __shared__ float t[32][33];
    const int tx = threadIdx.x & 31, ty = threadIdx.x >> 5;  // 32 x 8
    const int k0 = blockIdx.x * 32, n0 = blockIdx.y * 32;
    #pragma unroll
    for (int j = 0; j < 4; ++j)
        t[ty + j * 8][tx] = src[(size_t)(k0 + ty + j * 8) * DMODEL + n0 + tx];
    __syncthreads();
    #pragma unroll
    for (int j = 0; j < 4; ++j)
        out[(size_t)(n0 + ty + j * 8) * DMODEL + k0 + tx] = f2b(t[tx][ty + j * 8]);
}

// ---------------------------------------------------------------------------
// bf16 MFMA GEMM, direct-global fragments (no LDS).  (unchanged this round)
// A [M,K] bf16 row-major; Bt [N,K] bf16 (transposed weights). Block 256 = 4
// waves; wave covers 32 m-rows x 64 n-cols; block tile 128x64. BK=32.
// MODE 0: head-split bf16 store  C[((b*8+h)*2048+s)*64+d]
// MODE 1: V-transposed bf16 store Vt[((b*8+h)*64+d)*2048+s]
// MODE 2: bf16 store  C[m*N+n] = bf16(resid - (acc + bias[n]))
// MODE 3: f32 store   C[m*N+n] = acc + bias[n]
// ---------------------------------------------------------------------------
template <int MODE>
__launch_bounds__(256) __global__
void gemm_bf16(const unsigned short* __restrict__ A,
               const unsigned short* __restrict__ Bt,
               void* __restrict__ Cout, const float* __restrict__ bias,
               const float* __restrict__ resid, int M, int N, int K) {
    const int tid = threadIdx.x;
    const int w = tid >> 6, lane = tid & 63;
    const int l16 = lane & 15, q4 = lane >> 4;
    const int mBase = blockIdx.x * 128 + w * 32;
    const int n0 = blockIdx.y * 64;

    const unsigned short* Arow0 = A + (size_t)(mBase + l16) * K;
    const unsigned short* Arow1 = Arow0 + (size_t)16 * K;
    const unsigned short* Brow0 = Bt + (size_t)(n0 + l16) * K;

    f32x4 z = {0.f, 0.f, 0.f, 0.f};
    f32x4 acc[2][4];
    #pragma unroll
    for (int i = 0; i < 2; ++i)
        #pragma unroll
        for (int t = 0; t < 4; ++t) acc[i][t] = z;

    #pragma unroll 2
    for (int k0 = 0; k0 < K; k0 += 32) {
        const int ko = k0 + q4 * 8;
        short8 a0 = *(const short8*)(Arow0 + ko);
        short8 a1 = *(const short8*)(Arow1 + ko);
        #pragma unroll
        for (int t = 0; t < 4; ++t) {
            short8 b = *(const short8*)(Brow0 + (size_t)t * 16 * K + ko);
            acc[0][t] = MFMA16(a0, b, acc[0][t]);
            acc[1][t] = MFMA16(a1, b, acc[1][t]);
        }
    }

    #pragma unroll
    for (int i = 0; i < 2; ++i) {
        #pragma unroll
        for (int t = 0; t < 4; ++t) {
            #pragma unroll
            for (int r = 0; r < 4; ++r) {
                const int m = mBase + i * 16 + q4 * 4 + r;
                const int n = n0 + t * 16 + l16;
                float v = acc[i][t][r];
                if (MODE == 0) {
                    ((unsigned short*)Cout)[(((size_t)(m >> 11) * NH + (n >> 6)) * NQ + (m & 2047)) * DHEAD + (n & 63)] = f2b(v);
                } else if (MODE == 1) {
                    ((unsigned short*)Cout)[(((size_t)(m >> 11) * NH + (n >> 6)) * DHEAD + (n & 63)) * NKEY + (m & 2047)] = f2b(v);
                } else if (MODE == 2) {
                    ((unsigned short*)Cout)[(size_t)m * N + n] = f2b(resid[(size_t)m * N + n] - (v + bias[n]));
                } else {
                    ((float*)Cout)[(size_t)m * N + n] = v + bias[n];
                }
            }
        }
    }
}

// ---------------------------------------------------------------------------
// Pass 1: colSrcp[bh][k] = 1 / sum_q exp(S[q,k])  (no max subtraction; |S|<~10)
// Wave = 32 k-cols (2 B-frags, loaded ONCE); q-loop 32/iter: 8 MFMA + 16 exp.
// ---------------------------------------------------------------------------
__launch_bounds__(256) __global__
void attn_pass1(const unsigned short* __restrict__ Qh,
                const unsigned short* __restrict__ Kh,
                float* __restrict__ colSrcp) {
    const int tid = threadIdx.x;
    const int w = tid >> 6, lane = tid & 63;
    const int l16 = lane & 15, q4 = lane >> 4;
    const int bh = blockIdx.y;
    const int kcol0 = blockIdx.x * 128 + w * 32;

    // Persistent B-fragments: 32 k-cols x d=64  (4 short8)
    short8 bk[2][2];
    #pragma unroll
    for (int j = 0; j < 2; ++j) {
        const unsigned short* Krow = Kh + ((size_t)bh * NKEY + kcol0 + j * 16 + l16) * DHEAD;
        bk[j][0] = *(const short8*)(Krow + q4 * 8);
        bk[j][1] = *(const short8*)(Krow + 32 + q4 * 8);
    }
    const unsigned short* Qb = Qh + (size_t)bh * NQ * DHEAD;

    f32x4 z = {0.f, 0.f, 0.f, 0.f};
    float csum[2] = {0.f, 0.f};
    #pragma unroll 2
    for (int q0 = 0; q0 < NQ; q0 += 32) {
        short8 aq[2][2];
        #pragma unroll
        for (int i = 0; i < 2; ++i) {
            const unsigned short* Arow = Qb + (size_t)(q0 + i * 16 + l16) * DHEAD;
            aq[i][0] = *(const short8*)(Arow + q4 * 8);
            aq[i][1] = *(const short8*)(Arow + 32 + q4 * 8);
        }
        #pragma unroll
        for (int i = 0; i < 2; ++i) {
            #pragma unroll
            for (int j = 0; j < 2; ++j) {
                f32x4 s = MFMA16(aq[i][0], bk[j][0], z);
                s = MFMA16(aq[i][1], bk[j][1], s);
                csum[j] += __expf(s[0]) + __expf(s[1]) + __expf(s[2]) + __expf(s[3]);
            }
        }
    }
    #pragma unroll
    for (int j = 0; j < 2; ++j) {
        float c = csum[j];
        c += __shfl_xor(c, 16, 64);
        c += __shfl_xor(c, 32, 64);
        if (q4 == 0)
            colSrcp[(size_t)bh * NKEY + kcol0 + j * 16 + l16] = 1.0f / c;
    }
}

// ---------------------------------------------------------------------------
// Pass 2: E = exp(S)*colSrcp; r_q = sum_k E; O = E @ V; attnb = bf16(O/(1e-12+r_q))
// Wave = 32 q-rows. k-loop steps 64 = two 32-k sub-tiles with double-buffered
// wave-private E (no __syncthreads). K-frags + rcp for both sub-tiles hoisted.
// Per sub-tile: 8 QK MFMA, 16 exp, 16 ds_write_u16, 2 ds_read_b128, 8 PV MFMA.
// ---------------------------------------------------------------------------
__launch_bounds__(256) __global__
void attn_pass2(const unsigned short* __restrict__ Qh,
                const unsigned short* __restrict__ Kh,
                const unsigned short* __restrict__ Vt,
                const float* __restrict__ colSrcp,
                unsigned short* __restrict__ attnb) {
    __shared__ unsigned short Elds[4][2][32][40];  // [wave][buf][q][k pad40] = 20 KB
    const int tid = threadIdx.x;
    const int w = tid >> 6, lane = tid & 63;
    const int l16 = lane & 15, q4 = lane >> 4;
    const int bh = blockIdx.y;
    const int b = bh >> 3, h = bh & 7;
    const int q0w = blockIdx.x * 128 + w * 32;

    // Persistent A-fragments: 32 q-rows x d=64
    short8 aq[2][2];
    #pragma unroll
    for (int i = 0; i < 2; ++i) {
        const unsigned short* Qrow = Qh + ((size_t)bh * NQ + q0w + i * 16 + l16) * DHEAD;
        aq[i][0] = *(const short8*)(Qrow + q4 * 8);
        aq[i][1] = *(const short8*)(Qrow + 32 + q4 * 8);
    }
    const unsigned short* Kb = Kh + (size_t)bh * NKEY * DHEAD;
    const unsigned short* Vb = Vt + (size_t)bh * DHEAD * NKEY;
    const float* cs = colSrcp + (size_t)bh * NKEY;
    unsigned short* Ew = &Elds[w][0][0][0];

    f32x4 z = {0.f, 0.f, 0.f, 0.f};
    f32x4 o[2][4];
    #pragma unroll
    for (int i = 0; i < 2; ++i)
        #pragma unroll
        for (int t = 0; t < 4; ++t) o[i][t] = z;
    float rq[2][4] = {};

    for (int k0 = 0; k0 < NKEY; k0 += 64) {
        // hoisted K-fragments + rcp for BOTH 32-k sub-tiles
        short8 bk[2][2][2];
        float rcp[2][2];
        #pragma unroll
        for (int sub = 0; sub < 2; ++sub) {
            #pragma unroll
            for (int j = 0; j < 2; ++j) {
                const int kc = k0 + sub * 32 + j * 16;
                const unsigned short* Krow = Kb + (size_t)(kc + l16) * DHEAD;
                bk[sub][j][0] = *(const short8*)(Krow + q4 * 8);
                bk[sub][j][1] = *(const short8*)(Krow + 32 + q4 * 8);
                rcp[sub][j] = cs[kc + l16];
            }
        }
        #pragma unroll
        for (int sub = 0; sub < 2; ++sub) {
            const int kb = k0 + sub * 32;
            // V B-fragments (consumed after LDS round-trip: slack)
            short8 bv[4];
            #pragma unroll
            for (int t = 0; t < 4; ++t)
                bv[t] = *(const short8*)(Vb + (size_t)(t * 16 + l16) * NKEY + kb + q4 * 8);
            unsigned short* Eb = Ew + sub * (32 * 40);
            #pragma unroll
            for (int i = 0; i < 2; ++i) {
                #pragma unroll
                for (int j = 0; j < 2; ++j) {
                    f32x4 s = MFMA16(aq[i][0], bk[sub][j][0], z);
                    s = MFMA16(aq[i][1], bk[sub][j][1], s);
                    #pragma unroll
                    for (int r = 0; r < 4; ++r) {
                        float e = __expf(s[r]) * rcp[sub][j];
                        rq[i][r] += e;
                        Eb[(i * 16 + q4 * 4 + r) * 40 + j * 16 + l16] = f2b(e);
                    }
                }
            }
            #pragma unroll
            for (int i = 0; i < 2; ++i) {
                short8 ea = *(const short8*)(Eb + (i * 16 + l16) * 40 + q4 * 8);
                #pragma unroll
                for (int t = 0; t < 4; ++t)
                    o[i][t] = MFMA16(ea, bv[t], o[i][t]);
            }
        }
    }

    #pragma unroll
    for (int i = 0; i < 2; ++i)
        #pragma unroll
        for (int r = 0; r < 4; ++r) {
            float v = rq[i][r];
            v += __shfl_xor(v, 1, 64);
            v += __shfl_xor(v, 2, 64);
            v += __shfl_xor(v, 4, 64);
            v += __shfl_xor(v, 8, 64);
            rq[i][r] = 1.0f / (1e-12f + v);
        }
    #pragma unroll
    for (int i = 0; i < 2; ++i)
        #pragma unroll
        for (int t = 0; t < 4; ++t)
            #pragma unroll
            for (int r = 0; r < 4; ++r) {
                const int q = q0w + i * 16 + q4 * 4 + r;
                attnb[((size_t)b * NQ + q) * DMODEL + h * DHEAD + t * 16 + l16] =
                    f2b(o[i][t][r] * rq[i][r]);
            }
}

// ---------------------------------------------------------------------------
extern "C" void kernel_launch(void* const* d_in, const int* in_sizes, int n_in,
                              void* d_out, int out_size, void* d_ws, size_t ws_size,
                              hipStream_t stream) {
    const float* init_query = (const float*)d_in[0];
    const float* embedding  = (const float*)d_in[1];
    const float* Wq = (const float*)d_in[2];
    const float* Wk = (const float*)d_in[3];
    const float* Wv = (const float*)d_in[4];
    const float* W0 = (const float*)d_in[5];
    const float* b0 = (const float*)d_in[6];
    const float* W1 = (const float*)d_in[7];
    const float* b1 = (const float*)d_in[8];
    float* out = (float*)d_out;

    const size_t ACT = (size_t)BATCH * NQ * DMODEL;   // 4M elements
    const size_t WEL = (size_t)DMODEL * DMODEL;       // 256K elements

    unsigned short* Xq   = (unsigned short*)d_ws;          // bf16 init_query
    unsigned short* Xe   = Xq + ACT;                       // bf16 embedding
    unsigned short* Wt   = Xe + ACT;                       // 5 transposed weights
    unsigned short* Qh   = Wt + 5 * WEL;                   // [bh][q][d]
    unsigned short* Kh   = Qh + ACT;                       // [bh][k][d]
    unsigned short* Vtb  = Kh + ACT;                       // [bh][d][k]
    unsigned short* attnb= Vtb + ACT;                      // [8192][512]
    unsigned short* ybuf = attnb + ACT;                    // [8192][512]
    float* colSrcp = (float*)(ybuf + ACT);                 // [bh][k]

    unsigned short* Wqt = Wt + 0 * WEL;
    unsigned short* Wkt = Wt + 1 * WEL;
    unsigned short* Wvt = Wt + 2 * WEL;
    unsigned short* W0t = Wt + 3 * WEL;
    unsigned short* W1t = Wt + 4 * WEL;

    const int M = BATCH * NQ;  // 8192
    dim3 blk(256);
    dim3 gGemm(M / 128, DMODEL / 64);  // 64 x 8

    cast_x<<<dim3(ACT / 1024, 2), blk, 0, stream>>>(init_query, embedding, Xq, Xe);
    trans_w<<<dim3(16, 16, 5), blk, 0, stream>>>(Wq, Wk, Wv, W0, W1, Wt);

    gemm_bf16<0><<<gGemm, blk, 0, stream>>>(Xq, Wqt, Qh, nullptr, nullptr, M, DMODEL, DMODEL);
    gemm_bf16<0><<<gGemm, blk, 0, stream>>>(Xe, Wkt, Kh, nullptr, nullptr, M, DMODEL, DMODEL);
    gemm_bf16<1><<<gGemm, blk, 0, stream>>>(Xe, Wvt, Vtb, nullptr, nullptr, M, DMODEL, DMODEL);

    attn_pass1<<<dim3(NKEY / 128, BH), blk, 0, stream>>>(Qh, Kh, colSrcp);
    attn_pass2<<<dim3(NQ / 128, BH), blk, 0, stream>>>(Qh, Kh, Vtb, colSrcp, attnb);

    gemm_bf16<2><<<gGemm, blk, 0, stream>>>(attnb, W0t, ybuf, b0, init_query, M, DMODEL, DMODEL);
    gemm_bf16<3><<<gGemm, blk, 0, stream>>>(ybuf, W1t, out, b1, nullptr, M, DMODEL, DMODEL);
}